// Round 2
// baseline (248.201 us; speedup 1.0000x reference)
//
#include <hip/hip_runtime.h>
#include <hip/hip_fp16.h>
#include <math.h>

#define EH   65536
#define LAMF 5.0f
#define SVF  0.36787944117144233f   // exp(-0.2*5) = exp(-1)

typedef __bf16 bf16x8 __attribute__((ext_vector_type(8)));
typedef float  f32x4  __attribute__((ext_vector_type(4)));

__device__ __forceinline__ float sigmoidf_(float x) { return 1.0f / (1.0f + expf(-x)); }

__device__ __forceinline__ void cvt1(float v, ushort& h, ushort& l) {
    __bf16 bh = (__bf16)v;
    h = __builtin_bit_cast(ushort, bh);
    __bf16 bl = (__bf16)(v - (float)bh);
    l = __builtin_bit_cast(ushort, bl);
}

// ---------------- transpose + fp32 -> bf16 hi/lo ----------------------------
// in: [R][C] fp32 with leading dim ld ; out hi/lo: [C][R] bf16 (ld R)
__global__ __launch_bounds__(256) void cvtT_kernel(const float* __restrict__ in,
    int ld, int R, ushort* __restrict__ ohi, ushort* __restrict__ olo)
{
    __shared__ float t[32][33];
    const int tid = threadIdx.x;
    const int r0 = blockIdx.y * 32, c0 = blockIdx.x * 32;
    {
        int lr = tid >> 3, lc = (tid & 7) * 4;
        float4 v = *(const float4*)&in[(size_t)(r0 + lr) * ld + c0 + lc];
        t[lr][lc] = v.x; t[lr][lc+1] = v.y; t[lr][lc+2] = v.z; t[lr][lc+3] = v.w;
    }
    __syncthreads();
    int j = tid >> 3, i4 = (tid & 7) * 4;
    ushort4 h4, l4;
    cvt1(t[i4+0][j], h4.x, l4.x);
    cvt1(t[i4+1][j], h4.y, l4.y);
    cvt1(t[i4+2][j], h4.z, l4.z);
    cvt1(t[i4+3][j], h4.w, l4.w);
    size_t o = (size_t)(c0 + j) * R + r0 + i4;
    *(ushort4*)&ohi[o] = h4;
    *(ushort4*)&olo[o] = l4;
}

// ---------------- unified MFMA GEMM, 64x64 tile, split-precision ------------
// EPI 0: h = relu(A@B + bias)            (encoder)
// EPI 1: C = A@B                          (Hn|Hs fused, Aapp|Bapp fused)
// EPI 2: outm = relu(A@B + Hs + b_mp)     (agg; A switches ew2/ewT0 per row half)
// EPI 3: Mh = fp16(exp(sigmoid(cos,iou)@fin)*LAM)  (gram; B staged from fp32)
template<int EPI>
__global__ __launch_bounds__(256) void gemm_mfma(
    const float* __restrict__ Af, const float* __restrict__ Af2, int lda, int K,
    const ushort* __restrict__ BThi, const ushort* __restrict__ BTlo,
    const float* __restrict__ BTf, int ldbt, int koff128,
    const float* __restrict__ bias,
    const float* __restrict__ hsrc, int ldhs, const float* __restrict__ bmp,
    const float* __restrict__ norms, const float* __restrict__ iou,
    const float* __restrict__ finw, const float* __restrict__ finb,
    float* __restrict__ Cout, int ldc, __half* __restrict__ Mh)
{
    __shared__ ushort As_hi[64*40], As_lo[64*40], Bs_hi[64*40], Bs_lo[64*40];
    const int tid = threadIdx.x;
    const int row0 = blockIdx.y * 64, col0 = blockIdx.x * 64;

    const float* Abase = Af; int arow0 = row0;
    int kbase = 0, brow0 = col0;
    if (EPI == 2) {
        if (row0 >= 256) { Abase = Af2; arow0 = row0 - 256; }
        else kbase = 256;
    }
    if (EPI == 1 && koff128) { kbase = (col0 >> 7) * koff128; brow0 = col0 & 127; }

    f32x4 acc[2][2] = {};
    const int lane = tid & 63;
    const int w = tid >> 6;
    const int qr = (w >> 1) * 32, qc = (w & 1) * 32;
    const int fr = lane & 15, kg = (lane >> 4) * 8;

    for (int k0 = 0; k0 < K; k0 += 32) {
        // stage A: fp32 -> hi/lo bf16 into padded LDS
        #pragma unroll
        for (int c = tid; c < 512; c += 256) {
            int row = c >> 3, kq = (c & 7) * 4;
            float4 v = *(const float4*)&Abase[(size_t)(arow0 + row) * lda + k0 + kq];
            ushort4 h4, l4;
            cvt1(v.x, h4.x, l4.x); cvt1(v.y, h4.y, l4.y);
            cvt1(v.z, h4.z, l4.z); cvt1(v.w, h4.w, l4.w);
            *(ushort4*)&As_hi[row*40 + kq] = h4;
            *(ushort4*)&As_lo[row*40 + kq] = l4;
        }
        // stage B
        if (EPI == 3) {
            #pragma unroll
            for (int c = tid; c < 512; c += 256) {
                int row = c >> 3, kq = (c & 7) * 4;
                float4 v = *(const float4*)&BTf[(size_t)(col0 + row) * ldbt + k0 + kq];
                ushort4 h4, l4;
                cvt1(v.x, h4.x, l4.x); cvt1(v.y, h4.y, l4.y);
                cvt1(v.z, h4.z, l4.z); cvt1(v.w, h4.w, l4.w);
                *(ushort4*)&Bs_hi[row*40 + kq] = h4;
                *(ushort4*)&Bs_lo[row*40 + kq] = l4;
            }
        } else {
            int arr = tid >> 7, c = tid & 127;
            int row = c >> 1, sub = (c & 1) * 8;
            const ushort* s = (arr ? BTlo : BThi) + (size_t)(brow0 + row) * ldbt + kbase + k0 + sub;
            ushort* d = (arr ? Bs_lo : Bs_hi) + row*40 + sub;
            *(uint4*)d = *(const uint4*)s;
        }
        __syncthreads();
        bf16x8 ah[2], al[2], bh[2], bl[2];
        #pragma unroll
        for (int m = 0; m < 2; ++m) {
            int r = (qr + m*16 + fr) * 40 + kg;
            ah[m] = *(const bf16x8*)&As_hi[r];
            al[m] = *(const bf16x8*)&As_lo[r];
        }
        #pragma unroll
        for (int n = 0; n < 2; ++n) {
            int r = (qc + n*16 + fr) * 40 + kg;
            bh[n] = *(const bf16x8*)&Bs_hi[r];
            bl[n] = *(const bf16x8*)&Bs_lo[r];
        }
        #pragma unroll
        for (int m = 0; m < 2; ++m)
            #pragma unroll
            for (int n = 0; n < 2; ++n) {
                acc[m][n] = __builtin_amdgcn_mfma_f32_16x16x32_bf16(ah[m], bh[n], acc[m][n], 0, 0, 0);
                acc[m][n] = __builtin_amdgcn_mfma_f32_16x16x32_bf16(ah[m], bl[n], acc[m][n], 0, 0, 0);
                acc[m][n] = __builtin_amdgcn_mfma_f32_16x16x32_bf16(al[m], bh[n], acc[m][n], 0, 0, 0);
            }
        __syncthreads();
    }

    const int rbase = (lane >> 4) * 4;
    #pragma unroll
    for (int m = 0; m < 2; ++m)
        #pragma unroll
        for (int n = 0; n < 2; ++n)
            #pragma unroll
            for (int r = 0; r < 4; ++r) {
                int gr = row0 + qr + m*16 + rbase + r;
                int gc = col0 + qc + n*16 + (lane & 15);
                float v = acc[m][n][r];
                if (EPI == 0) {
                    Cout[(size_t)gr*ldc + gc] = fmaxf(v + bias[gc], 0.f);
                } else if (EPI == 1) {
                    Cout[(size_t)gr*ldc + gc] = v;
                } else if (EPI == 2) {
                    v += hsrc[(size_t)gr*ldhs + gc] + bmp[gc];
                    Cout[(size_t)gr*ldc + gc] = fmaxf(v, 0.f);
                } else {
                    float cosv = v / (norms[gr] * norms[256 + gc]);
                    float fin = sigmoidf_(cosv * finw[0] + iou[gr*256 + gc] * finw[1] + finb[0]);
                    Mh[gr*256 + gc] = __float2half(expf(fin * LAMF));
                }
            }
}

// ---------------- geo tiny GEMM ---------------------------------------------
__global__ __launch_bounds__(256) void geo_kernel(const float* __restrict__ coords,
    const float* __restrict__ geo_W1, const float* __restrict__ geo_b1,
    float* __restrict__ geoA, float* __restrict__ geoB)
{
    int idx = blockIdx.x * 256 + threadIdx.x;
    int half = idx >> 15;
    int rem  = idx & 32767;
    int n = rem >> 6, j = rem & 63;
    float4 cv = *(const float4*)&coords[n * 4];
    const float* W = geo_W1 + half * 4 * 64;
    float v = cv.x * W[j] + cv.y * W[64 + j] + cv.z * W[128 + j] + cv.w * W[192 + j];
    if (half == 0) geoA[n * 64 + j] = v + geo_b1[j];
    else           geoB[n * 64 + j] = v;
}

// ---------------- per-edge ew + iou -----------------------------------------
__global__ __launch_bounds__(256) void edge_kernel(
    const float* __restrict__ C23, const float* __restrict__ geoA, const float* __restrict__ geoB,
    const float* __restrict__ app_b1, const float* __restrict__ app_w2, const float* __restrict__ app_b2,
    const float* __restrict__ geo_w2, const float* __restrict__ geo_b2,
    const float* __restrict__ aff_w, const float* __restrict__ aff_b,
    const float* __restrict__ co, float* __restrict__ ewT0, float* __restrict__ ew2,
    float* __restrict__ iou1)
{
    __shared__ float sA[16][129], sB[16][129], sGA[16][65], sGB[16][65];
    __shared__ float sw2[128], sb1[128], sgw2[64];
    const int tid = threadIdx.x;
    const int half = blockIdx.z;
    const int t0 = blockIdx.y * 16, d0 = blockIdx.x * 16;
    const int sbase = half ? (256 + d0) : t0;   // source-node rows
    const int dbase = half ? t0 : (256 + d0);   // dest-node rows
    for (int i = tid; i < 16 * 32; i += 256) {
        int rr = i >> 5, c4 = (i & 31) << 2;
        float4 va = *(const float4*)&C23[(sbase + rr) * 256 + c4];
        sA[rr][c4] = va.x; sA[rr][c4+1] = va.y; sA[rr][c4+2] = va.z; sA[rr][c4+3] = va.w;
        float4 vb = *(const float4*)&C23[(dbase + rr) * 256 + 128 + c4];
        sB[rr][c4] = vb.x; sB[rr][c4+1] = vb.y; sB[rr][c4+2] = vb.z; sB[rr][c4+3] = vb.w;
    }
    for (int i = tid; i < 16 * 16; i += 256) {
        int rr = i >> 4, c4 = (i & 15) << 2;
        float4 va = *(const float4*)&geoA[(sbase + rr) * 64 + c4];
        sGA[rr][c4] = va.x; sGA[rr][c4+1] = va.y; sGA[rr][c4+2] = va.z; sGA[rr][c4+3] = va.w;
        float4 vb = *(const float4*)&geoB[(dbase + rr) * 64 + c4];
        sGB[rr][c4] = vb.x; sGB[rr][c4+1] = vb.y; sGB[rr][c4+2] = vb.z; sGB[rr][c4+3] = vb.w;
    }
    if (tid < 128) { sw2[tid] = app_w2[tid]; sb1[tid] = app_b1[tid]; }
    else if (tid < 192) sgw2[tid - 128] = geo_w2[tid - 128];
    __syncthreads();
    const int tx = tid & 15, ty = tid >> 4;
    const int si = half ? tx : ty;
    const int di = half ? ty : tx;
    float acc1 = 0.f;
    #pragma unroll 8
    for (int j = 0; j < 128; ++j) {
        float v = sA[si][j] + sB[di][j] + sb1[j];
        acc1 += fmaxf(v, 0.f) * sw2[j];
    }
    float x1 = sigmoidf_(acc1 + app_b2[0]);
    float acc2 = 0.f;
    #pragma unroll 8
    for (int j = 0; j < 64; ++j) {
        float v = sGA[si][j] + sGB[di][j];
        acc2 += fmaxf(v, 0.f) * sgw2[j];
    }
    float x2 = sigmoidf_(acc2 + geo_b2[0]);
    float e = sigmoidf_(x1 * aff_w[0] + x2 * aff_w[1] + aff_b[0]);
    const int t = t0 + ty, d = d0 + tx;
    if (half) ew2[t * 256 + d] = e;
    else      ewT0[d * 256 + t] = e;
    if (half == 0) {
        float4 a = *(const float4*)&co[t * 4];
        float4 b = *(const float4*)&co[(256 + d) * 4];
        float ltx = fmaxf(a.x, b.x), lty = fmaxf(a.y, b.y);
        float rbx = fminf(a.z, b.z), rby = fminf(a.w, b.w);
        float w  = fmaxf(rbx - ltx, 0.f), hh = fmaxf(rby - lty, 0.f);
        float inter = w * hh;
        float areaA = (a.z - a.x) * (a.w - a.y);
        float areaB = (b.z - b.x) * (b.w - b.y);
        iou1[t * 256 + d] = inter / (areaA + areaB - inter + 1e-6f);
    }
}

// ---------------- row norms of outm -----------------------------------------
__global__ __launch_bounds__(256) void norm_kernel(const float* __restrict__ outm,
    float* __restrict__ norms)
{
    const int w = (blockIdx.x * 256 + threadIdx.x) >> 6;
    const int lane = threadIdx.x & 63;
    const float* rp = &outm[w * 512];
    float s = 0.f;
    #pragma unroll
    for (int i = 0; i < 8; ++i) { float v = rp[i * 64 + lane]; s += v * v; }
    #pragma unroll
    for (int o = 32; o > 0; o >>= 1) s += __shfl_down(s, o);
    if (lane == 0) norms[w] = fmaxf(sqrtf(s), 1e-6f);
}

// ---------------- Sinkhorn: single block, M0 fp16 in LDS --------------------
#define SINK_LDS (256 * 258 * 2 + (257 + 257 + 16) * 4)
__global__ __launch_bounds__(512) void sinkhorn_kernel(const __half* __restrict__ Mh,
    float* __restrict__ gr, float* __restrict__ gc)
{
    extern __shared__ char smem[];
    __half* Ms = (__half*)smem;                       // [256][258]
    float* r   = (float*)(smem + 256 * 258 * 2);      // [257]
    float* c   = r + 257;
    float* red = c + 257;
    const int tid = threadIdx.x;
    for (int i = tid; i < 8192; i += 512) {
        uint4 v = ((const uint4*)Mh)[i];
        int t = i >> 5, d = (i & 31) << 3;
        uint* dst = (uint*)&Ms[t * 258 + d];
        dst[0] = v.x; dst[1] = v.y; dst[2] = v.z; dst[3] = v.w;
    }
    if (tid <= 256) c[tid] = 1.0f;
    if (tid == 0) red[8] = 257.0f;
    __syncthreads();

    for (int it = 0; it < 8; ++it) {
        {
            float c256 = c[256];
            float Sc = red[8];
            int row = tid >> 1, sub = tid & 1;
            const __half2* rp = (const __half2*)&Ms[row * 258 + sub * 128];
            const float* cp = &c[sub * 128];
            float acc = 0.f;
            #pragma unroll 8
            for (int p = 0; p < 64; ++p) {
                float2 f = __half22float2(rp[p]);
                acc += f.x * cp[2*p] + f.y * cp[2*p + 1];
            }
            acc += __shfl_xor(acc, 1);
            if (sub == 0) r[row] = 1.0f / (acc + SVF * c256);
            if (tid == 511) r[256] = 1.0f / (SVF * Sc);
        }
        __syncthreads();
        if (tid < 64) {
            float s = r[tid] + r[tid + 64] + r[tid + 128] + r[tid + 192];
            if (tid == 0) s += r[256];
            #pragma unroll
            for (int o = 32; o > 0; o >>= 1) s += __shfl_down(s, o);
            if (tid == 0) red[9] = s;
        }
        __syncthreads();
        {
            float r256 = r[256];
            float Sr = red[9];
            int dp = tid >> 2, sub = tid & 3;
            const __half* base = &Ms[(sub * 64) * 258 + 2 * dp];
            float a0 = 0.f, a1 = 0.f;
            #pragma unroll 8
            for (int k = 0; k < 64; ++k) {
                float2 f = __half22float2(*(const __half2*)(base + k * 258));
                float rv = r[sub * 64 + k];
                a0 += f.x * rv; a1 += f.y * rv;
            }
            a0 += __shfl_xor(a0, 1); a0 += __shfl_xor(a0, 2);
            a1 += __shfl_xor(a1, 1); a1 += __shfl_xor(a1, 2);
            if (sub == 0) {
                c[2*dp]     = 1.0f / (a0 + SVF * r256);
                c[2*dp + 1] = 1.0f / (a1 + SVF * r256);
            }
            if (tid == 511) c[256] = 1.0f / (SVF * Sr);
        }
        __syncthreads();
        if (tid < 64) {
            float s = c[tid] + c[tid + 64] + c[tid + 128] + c[tid + 192];
            if (tid == 0) s += c[256];
            #pragma unroll
            for (int o = 32; o > 0; o >>= 1) s += __shfl_down(s, o);
            if (tid == 0) red[8] = s;
        }
        __syncthreads();
    }
    if (tid <= 256) { gr[tid] = r[tid]; gc[tid] = c[tid]; }
}

// ---------------- final output assembly -------------------------------------
__global__ __launch_bounds__(256) void final_kernel(const __half* __restrict__ Mh,
    const float* __restrict__ r, const float* __restrict__ c,
    const float* __restrict__ gt, float* __restrict__ out)
{
    const int bid = blockIdx.x, tid = threadIdx.x;
    if (bid < 256) {
        int k = bid * 256 + tid;
        out[k] = __half2float(Mh[k]) * r[bid] * c[tid];
    } else if (bid < 512) {
        int k = (bid - 256) * 256 + tid;
        out[EH + k] = gt[k];
    } else if (tid == 0) {
        out[2 * EH]     = 256.0f;
        out[2 * EH + 1] = 256.0f;
    }
}

extern "C" void kernel_launch(void* const* d_in, const int* in_sizes, int n_in,
                              void* d_out, int out_size, void* d_ws, size_t ws_size,
                              hipStream_t stream)
{
    const float* x       = (const float*)d_in[0];
    const float* coords  = (const float*)d_in[1];
    const float* co      = (const float*)d_in[2];
    const float* gt      = (const float*)d_in[3];
    const float* W_enc   = (const float*)d_in[5];
    const float* b_enc   = (const float*)d_in[6];
    const float* app_W1  = (const float*)d_in[7];
    const float* app_b1  = (const float*)d_in[8];
    const float* app_w2  = (const float*)d_in[9];
    const float* app_b2  = (const float*)d_in[10];
    const float* geo_W1  = (const float*)d_in[11];
    const float* geo_b1  = (const float*)d_in[12];
    const float* geo_w2  = (const float*)d_in[13];
    const float* geo_b2  = (const float*)d_in[14];
    const float* aff_w   = (const float*)d_in[15];
    const float* aff_b   = (const float*)d_in[16];
    const float* W_self  = (const float*)d_in[17];
    const float* W_nbr   = (const float*)d_in[18];
    const float* b_mp    = (const float*)d_in[19];
    const float* fin_w   = (const float*)d_in[20];
    const float* fin_b   = (const float*)d_in[21];
    float* out = (float*)d_out;

    // ---- workspace layout (byte offsets; stream-order-safe aliasing, peak 5.90 MB)
    char* W = (char*)d_ws;
    ushort* WencT_hi = (ushort*)(W + 0);        // [512][2048]   phase 1
    ushort* WencT_lo = (ushort*)(W + 2097152);
    float*  h        = (float*)(W + 4849664);   // [512][512]
    ushort* WnsT_hi  = (ushort*)(W + 0);        // [1024][512]   phase 2 (aliases WencT)
    ushort* WnsT_lo  = (ushort*)(W + 1048576);
    ushort* W1T_hi   = (ushort*)(W + 2097152);  // [128][1024]
    ushort* W1T_lo   = (ushort*)(W + 2359296);
    float*  C45      = (float*)(W + 2621440);   // [512][1024]  (Hn | Hs)
    float*  C23      = (float*)(W + 0);         // [512][256]   (Aapp | Bapp)
    ushort* HnT_hi   = (ushort*)(W + 524288);   // [512][512]
    ushort* HnT_lo   = (ushort*)(W + 1048576);
    float*  geoA     = (float*)(W + 1572864);
    float*  geoB     = (float*)(W + 1703936);
    float*  ewT0     = (float*)(W + 1835008);   // [256 d][256 t]
    float*  ew2      = (float*)(W + 2097152);   // [256 t][256 d]
    float*  iou1     = (float*)(W + 2359296);   // [256][256]
    float*  outm     = (float*)(W + 4849664);   // [512][512]  (aliases h)
    float*  norms    = (float*)(W + 0);
    __half* Mh       = (__half*)(W + 4718592);  // [256][256]
    float*  gr       = (float*)(W + 2048);
    float*  gc       = (float*)(W + 4096);

    // 1) W_enc^T hi/lo
    cvtT_kernel<<<dim3(16, 64), 256, 0, stream>>>(W_enc, 512, 2048, WencT_hi, WencT_lo);
    // 2) h = relu(x @ W_enc + b_enc)     M=512 N=512 K=2048
    gemm_mfma<0><<<dim3(8, 8), 256, 0, stream>>>(x, nullptr, 2048, 2048,
        WencT_hi, WencT_lo, nullptr, 2048, 0, b_enc,
        nullptr, 0, nullptr, nullptr, nullptr, nullptr, nullptr, h, 512, nullptr);
    // 3) [W_nbr; W_self]^T hi/lo
    cvtT_kernel<<<dim3(16, 16), 256, 0, stream>>>(W_nbr, 512, 512, WnsT_hi, WnsT_lo);
    cvtT_kernel<<<dim3(16, 16), 256, 0, stream>>>(W_self, 512, 512,
        WnsT_hi + (size_t)512 * 512, WnsT_lo + (size_t)512 * 512);
    // 4) app_W1^T hi/lo  [128][1024]
    cvtT_kernel<<<dim3(4, 32), 256, 0, stream>>>(app_W1, 128, 1024, W1T_hi, W1T_lo);
    // 5) C45 = h @ [W_nbr | W_self]      M=512 N=1024 K=512
    gemm_mfma<1><<<dim3(16, 8), 256, 0, stream>>>(h, nullptr, 512, 512,
        WnsT_hi, WnsT_lo, nullptr, 512, 0, nullptr,
        nullptr, 0, nullptr, nullptr, nullptr, nullptr, nullptr, C45, 1024, nullptr);
    // 6) C23 = h @ [W1a | W1b]           M=512 N=256 K=512
    gemm_mfma<1><<<dim3(4, 8), 256, 0, stream>>>(h, nullptr, 512, 512,
        W1T_hi, W1T_lo, nullptr, 1024, 512, nullptr,
        nullptr, 0, nullptr, nullptr, nullptr, nullptr, nullptr, C23, 256, nullptr);
    // 7) Hn^T hi/lo (Hn = C45 cols 0..511, ld 1024)
    cvtT_kernel<<<dim3(16, 16), 256, 0, stream>>>(C45, 1024, 512, HnT_hi, HnT_lo);
    // 8) geo features
    geo_kernel<<<256, 256, 0, stream>>>(coords, geo_W1, geo_b1, geoA, geoB);
    // 9) per-edge ew + iou
    edge_kernel<<<dim3(16, 16, 2), 256, 0, stream>>>(C23, geoA, geoB,
        app_b1, app_w2, app_b2, geo_w2, geo_b2, aff_w, aff_b, co, ewT0, ew2, iou1);
    // 10) outm = relu(agg + Hs + b_mp)   M=512 N=512 K=256
    gemm_mfma<2><<<dim3(8, 8), 256, 0, stream>>>(ew2, ewT0, 256, 256,
        HnT_hi, HnT_lo, nullptr, 512, 0, nullptr,
        C45 + 512, 1024, b_mp, nullptr, nullptr, nullptr, nullptr, outm, 512, nullptr);
    // 11) row norms
    norm_kernel<<<128, 256, 0, stream>>>(outm, norms);
    // 12) Gram + fin + M0(fp16)          M=256 N=256 K=512
    gemm_mfma<3><<<dim3(4, 4), 256, 0, stream>>>(outm, nullptr, 512, 512,
        nullptr, nullptr, outm + (size_t)256 * 512, 512, 0, nullptr,
        nullptr, 0, nullptr, norms, iou1, fin_w, fin_b, nullptr, 0, Mh);
    // 13) Sinkhorn scale vectors
    hipFuncSetAttribute(reinterpret_cast<const void*>(sinkhorn_kernel),
                        hipFuncAttributeMaxDynamicSharedMemorySize, SINK_LDS);
    sinkhorn_kernel<<<1, 512, SINK_LDS, stream>>>(Mh, gr, gc);
    // 14) final output assembly
    final_kernel<<<513, 256, 0, stream>>>(Mh, gr, gc, gt, out);
}

// Round 3
// 133.747 us; speedup vs baseline: 1.8558x; 1.8558x over previous
//
#include <hip/hip_runtime.h>
#include <hip/hip_fp16.h>
#include <math.h>

#define EH   65536
#define LAMF 5.0f
#define SVF  0.36787944117144233f   // exp(-0.2*5) = exp(-1)

typedef __bf16 bf16x8 __attribute__((ext_vector_type(8)));
typedef float  f32x4  __attribute__((ext_vector_type(4)));

__device__ __forceinline__ float sigmoidf_(float x) { return 1.0f / (1.0f + expf(-x)); }

__device__ __forceinline__ void cvt1(float v, ushort& h, ushort& l) {
    __bf16 bh = (__bf16)v;
    h = __builtin_bit_cast(ushort, bh);
    __bf16 bl = (__bf16)(v - (float)bh);
    l = __builtin_bit_cast(ushort, bl);
}

// ============ unified 64x64 MFMA GEMM, split-bf16, reg-prefetch =============
// MODE 0: encoder partial  P[z] = x @ W_enc(k-slice)          grid(8,8,4)
// MODE 1: C45|C23 fused    [h@Wnbr | h@Wself | h@W1a | h@W1b] grid(20,8)
// MODE 2: agg + epilogue   outm = relu(ew@Hn + Hs + b_mp)     grid(8,8)
#define LSTR 40   // LDS row stride in ushorts (80B: 16B-aligned rows)
template<int MODE>
__global__ __launch_bounds__(256) void gemm64(
    const float* __restrict__ Aa, const float* __restrict__ Ab,
    const float* __restrict__ B0, const float* __restrict__ B1,
    const float* __restrict__ B2,
    const float* __restrict__ HsC45, const float* __restrict__ bmp,
    float* __restrict__ C0, float* __restrict__ C1)
{
    __shared__ ushort As_hi[64*LSTR], As_lo[64*LSTR], Bs_hi[64*LSTR], Bs_lo[64*LSTR];
    const int tid = threadIdx.x;
    const int row0 = blockIdx.y * 64;

    const float* Ap = Aa; int lda, arow0 = row0, ak = 0;
    const float* Bp; int ldb, kb = 0, bcol0;
    float* Cp; int ldc, ccol0;
    int KS;

    if (MODE == 0) {
        KS = 512; lda = 2048; ak = blockIdx.z * 512;
        Bp = B0; ldb = 512; kb = blockIdx.z * 512; bcol0 = blockIdx.x * 64;
        Cp = C0 + blockIdx.z * 262144; ldc = 512; ccol0 = bcol0;
    } else if (MODE == 1) {
        KS = 512; lda = 512;
        int cb = blockIdx.x;
        if (cb < 8)       { Bp=B0; ldb=512; kb=0;   bcol0=cb*64;        Cp=C0; ldc=1024; ccol0=cb*64; }
        else if (cb < 16) { Bp=B1; ldb=512; kb=0;   bcol0=(cb-8)*64;    Cp=C0; ldc=1024; ccol0=512+(cb-8)*64; }
        else if (cb < 18) { Bp=B2; ldb=128; kb=0;   bcol0=(cb-16)*64;   Cp=C1; ldc=256;  ccol0=(cb-16)*64; }
        else              { Bp=B2; ldb=128; kb=512; bcol0=(cb-18)*64;   Cp=C1; ldc=256;  ccol0=128+(cb-18)*64; }
    } else {
        KS = 256; lda = 256;
        if (row0 < 256) { Ap = Aa; arow0 = row0;       kb = 256; }
        else            { Ap = Ab; arow0 = row0 - 256; kb = 0; }
        Bp = B0; ldb = 1024; bcol0 = blockIdx.x * 64;
        Cp = C0; ldc = 512; ccol0 = bcol0;
    }

    const int arow = tid >> 2, kq = (tid & 3) * 8;          // A-stage map
    const int kr = (tid & 15) * 2, nc0 = (tid >> 4) * 4;    // B-stage map (transpose)
    const float* aptr = Ap + (size_t)(arow0 + arow) * lda + ak + kq;
    const float* bptr = Bp + (size_t)(kb + kr) * ldb + bcol0 + nc0;

    f32x4 acc[2][2] = {};
    const int lane = tid & 63, w = tid >> 6;
    const int qr = (w >> 1) * 32, qc = (w & 1) * 32;
    const int fr = lane & 15, kg = (lane >> 4) * 8;

    float4 pa0, pa1, pb0, pb1;
    pa0 = *(const float4*)aptr; pa1 = *(const float4*)(aptr + 4);
    pb0 = *(const float4*)bptr; pb1 = *(const float4*)(bptr + ldb);

    for (int k0 = 0; k0 < KS; k0 += 32) {
        // ---- store staged tile (cvt fp32 -> hi/lo bf16)
        {
            ushort4 h0, l0, h1, l1;
            cvt1(pa0.x,h0.x,l0.x); cvt1(pa0.y,h0.y,l0.y); cvt1(pa0.z,h0.z,l0.z); cvt1(pa0.w,h0.w,l0.w);
            cvt1(pa1.x,h1.x,l1.x); cvt1(pa1.y,h1.y,l1.y); cvt1(pa1.z,h1.z,l1.z); cvt1(pa1.w,h1.w,l1.w);
            *(ushort4*)&As_hi[arow*LSTR + kq]     = h0;
            *(ushort4*)&As_hi[arow*LSTR + kq + 4] = h1;
            *(ushort4*)&As_lo[arow*LSTR + kq]     = l0;
            *(ushort4*)&As_lo[arow*LSTR + kq + 4] = l1;
            float b0a[4] = {pb0.x, pb0.y, pb0.z, pb0.w};
            float b1a[4] = {pb1.x, pb1.y, pb1.z, pb1.w};
            #pragma unroll
            for (int j = 0; j < 4; ++j) {
                ushort ha, la, hb, lb;
                cvt1(b0a[j], ha, la); cvt1(b1a[j], hb, lb);
                *(uint*)&Bs_hi[(nc0+j)*LSTR + kr] = (uint)ha | ((uint)hb << 16);
                *(uint*)&Bs_lo[(nc0+j)*LSTR + kr] = (uint)la | ((uint)lb << 16);
            }
        }
        __syncthreads();
        if (k0 + 32 < KS) {   // prefetch next tile (overlaps MFMA + barrier)
            pa0 = *(const float4*)(aptr + k0 + 32);
            pa1 = *(const float4*)(aptr + k0 + 36);
            const float* bp2 = bptr + (size_t)(k0 + 32) * ldb;
            pb0 = *(const float4*)bp2; pb1 = *(const float4*)(bp2 + ldb);
        }
        bf16x8 ah[2], al[2], bh[2], bl[2];
        #pragma unroll
        for (int m = 0; m < 2; ++m) {
            int r = (qr + m*16 + fr) * LSTR + kg;
            ah[m] = *(const bf16x8*)&As_hi[r];
            al[m] = *(const bf16x8*)&As_lo[r];
        }
        #pragma unroll
        for (int n = 0; n < 2; ++n) {
            int r = (qc + n*16 + fr) * LSTR + kg;
            bh[n] = *(const bf16x8*)&Bs_hi[r];
            bl[n] = *(const bf16x8*)&Bs_lo[r];
        }
        #pragma unroll
        for (int m = 0; m < 2; ++m)
            #pragma unroll
            for (int n = 0; n < 2; ++n) {
                acc[m][n] = __builtin_amdgcn_mfma_f32_16x16x32_bf16(ah[m], bh[n], acc[m][n], 0, 0, 0);
                acc[m][n] = __builtin_amdgcn_mfma_f32_16x16x32_bf16(ah[m], bl[n], acc[m][n], 0, 0, 0);
                acc[m][n] = __builtin_amdgcn_mfma_f32_16x16x32_bf16(al[m], bh[n], acc[m][n], 0, 0, 0);
            }
        __syncthreads();
    }

    const int rbase = (lane >> 4) * 4;
    #pragma unroll
    for (int m = 0; m < 2; ++m)
        #pragma unroll
        for (int n = 0; n < 2; ++n)
            #pragma unroll
            for (int r = 0; r < 4; ++r) {
                int gr = row0 + qr + m*16 + rbase + r;
                int gc = ccol0 + qc + n*16 + (lane & 15);
                float v = acc[m][n][r];
                if (MODE == 2) {
                    v += HsC45[(size_t)gr * 1024 + 512 + gc] + bmp[gc];
                    v = fmaxf(v, 0.f);
                }
                Cp[(size_t)gr * ldc + gc] = v;
            }
}

// ============ encoder split-K reduce: h = relu(sum P + bias) ================
__global__ __launch_bounds__(256) void enc_reduce(const float* __restrict__ P,
    const float* __restrict__ bias, float* __restrict__ h)
{
    int e = (blockIdx.x * 256 + threadIdx.x) * 4;
    int col = e & 511;
    float4 v0 = *(const float4*)&P[e];
    float4 v1 = *(const float4*)&P[e + 262144];
    float4 v2 = *(const float4*)&P[e + 524288];
    float4 v3 = *(const float4*)&P[e + 786432];
    float4 b  = *(const float4*)&bias[col];
    float4 o;
    o.x = fmaxf(v0.x + v1.x + v2.x + v3.x + b.x, 0.f);
    o.y = fmaxf(v0.y + v1.y + v2.y + v3.y + b.y, 0.f);
    o.z = fmaxf(v0.z + v1.z + v2.z + v3.z + b.z, 0.f);
    o.w = fmaxf(v0.w + v1.w + v2.w + v3.w + b.w, 0.f);
    *(float4*)&h[e] = o;
}

// ============ per-edge ew + iou (geo MLP inlined) ============================
__global__ __launch_bounds__(256) void edge_geo_kernel(
    const float* __restrict__ C23, const float* __restrict__ coords,
    const float* __restrict__ geo_W1, const float* __restrict__ geo_b1,
    const float* __restrict__ app_b1, const float* __restrict__ app_w2,
    const float* __restrict__ app_b2, const float* __restrict__ geo_w2,
    const float* __restrict__ geo_b2, const float* __restrict__ aff_w,
    const float* __restrict__ aff_b, const float* __restrict__ co,
    float* __restrict__ ewT0, float* __restrict__ ew2, float* __restrict__ iou1)
{
    __shared__ float sA[16][129], sB[16][129], sGA[16][65], sGB[16][65];
    __shared__ float sw2[128], sb1[128], sgw2[64];
    __shared__ float sgw[8][64], sgb[64], scs[16][4], scd[16][4];
    const int tid = threadIdx.x;
    const int half = blockIdx.z;
    const int t0 = blockIdx.y * 16, d0 = blockIdx.x * 16;
    const int sbase = half ? (256 + d0) : t0;   // source-node rows
    const int dbase = half ? t0 : (256 + d0);   // dest-node rows
    for (int i = tid; i < 16 * 32; i += 256) {
        int rr = i >> 5, c4 = (i & 31) << 2;
        float4 va = *(const float4*)&C23[(sbase + rr) * 256 + c4];
        sA[rr][c4] = va.x; sA[rr][c4+1] = va.y; sA[rr][c4+2] = va.z; sA[rr][c4+3] = va.w;
        float4 vb = *(const float4*)&C23[(dbase + rr) * 256 + 128 + c4];
        sB[rr][c4] = vb.x; sB[rr][c4+1] = vb.y; sB[rr][c4+2] = vb.z; sB[rr][c4+3] = vb.w;
    }
    for (int i = tid; i < 512; i += 256) sgw[i >> 6][i & 63] = geo_W1[i];
    if (tid < 64) sgb[tid] = geo_b1[tid];
    else if (tid < 192) { sw2[tid-64] = app_w2[tid-64]; sb1[tid-64] = app_b1[tid-64]; }
    else { sgw2[tid - 192] = geo_w2[tid - 192]; }
    if (tid < 64) scs[tid >> 2][tid & 3] = coords[(sbase + (tid >> 2)) * 4 + (tid & 3)];
    else if (tid < 128) { int i = tid - 64; scd[i >> 2][i & 3] = coords[(dbase + (i >> 2)) * 4 + (i & 3)]; }
    __syncthreads();
    for (int v = tid; v < 2048; v += 256) {
        int hh = v >> 10, rr = (v >> 6) & 15, j = v & 63;
        if (hh == 0) {
            sGA[rr][j] = scs[rr][0]*sgw[0][j] + scs[rr][1]*sgw[1][j]
                       + scs[rr][2]*sgw[2][j] + scs[rr][3]*sgw[3][j] + sgb[j];
        } else {
            sGB[rr][j] = scd[rr][0]*sgw[4][j] + scd[rr][1]*sgw[5][j]
                       + scd[rr][2]*sgw[6][j] + scd[rr][3]*sgw[7][j];
        }
    }
    __syncthreads();
    const int tx = tid & 15, ty = tid >> 4;
    const int si = half ? tx : ty;
    const int di = half ? ty : tx;
    float acc1 = 0.f;
    #pragma unroll 8
    for (int j = 0; j < 128; ++j) {
        float v = sA[si][j] + sB[di][j] + sb1[j];
        acc1 += fmaxf(v, 0.f) * sw2[j];
    }
    float x1 = sigmoidf_(acc1 + app_b2[0]);
    float acc2 = 0.f;
    #pragma unroll 8
    for (int j = 0; j < 64; ++j) {
        float v = sGA[si][j] + sGB[di][j];
        acc2 += fmaxf(v, 0.f) * sgw2[j];
    }
    float x2 = sigmoidf_(acc2 + geo_b2[0]);
    float e = sigmoidf_(x1 * aff_w[0] + x2 * aff_w[1] + aff_b[0]);
    const int t = t0 + ty, d = d0 + tx;
    if (half) ew2[t * 256 + d] = e;
    else      ewT0[d * 256 + t] = e;
    if (half == 0) {
        float4 a = *(const float4*)&co[t * 4];
        float4 b = *(const float4*)&co[(256 + d) * 4];
        float ltx = fmaxf(a.x, b.x), lty = fmaxf(a.y, b.y);
        float rbx = fminf(a.z, b.z), rby = fminf(a.w, b.w);
        float w  = fmaxf(rbx - ltx, 0.f), hh = fmaxf(rby - lty, 0.f);
        float inter = w * hh;
        float areaA = (a.z - a.x) * (a.w - a.y);
        float areaB = (b.z - b.x) * (b.w - b.y);
        iou1[t * 256 + d] = inter / (areaA + areaB - inter + 1e-6f);
    }
}

// ============ gram 32x32 + in-kernel norms + fin/exp epilogue ===============
__global__ __launch_bounds__(256) void gram32(const float* __restrict__ outm,
    const float* __restrict__ iou, const float* __restrict__ finw,
    const float* __restrict__ finb, __half* __restrict__ Mh)
{
    __shared__ ushort As_hi[32*LSTR], As_lo[32*LSTR], Bs_hi[32*LSTR], Bs_lo[32*LSTR];
    __shared__ float snA[32], snB[32];
    const int tid = threadIdx.x;
    const int t0 = blockIdx.y * 32, d0 = blockIdx.x * 32;
    const float* Asrc = outm;
    const float* Bsrc = outm + (size_t)256 * 512;

    const int arow = tid >> 3, kq = (tid & 7) * 4;
    const float* aptr = Asrc + (size_t)(t0 + arow) * 512 + kq;
    const float* bptr = Bsrc + (size_t)(d0 + arow) * 512 + kq;

    f32x4 acc = {};
    float ssA = 0.f, ssB = 0.f;
    const int lane = tid & 63, w = tid >> 6;
    const int qr = (w >> 1) * 16, qc = (w & 1) * 16;
    const int fr = lane & 15, kg = (lane >> 4) * 8;

    float4 pa = *(const float4*)aptr;
    float4 pb = *(const float4*)bptr;

    for (int k0 = 0; k0 < 512; k0 += 32) {
        ssA += pa.x*pa.x + pa.y*pa.y + pa.z*pa.z + pa.w*pa.w;
        ssB += pb.x*pb.x + pb.y*pb.y + pb.z*pb.z + pb.w*pb.w;
        {
            ushort4 h4, l4;
            cvt1(pa.x,h4.x,l4.x); cvt1(pa.y,h4.y,l4.y); cvt1(pa.z,h4.z,l4.z); cvt1(pa.w,h4.w,l4.w);
            *(ushort4*)&As_hi[arow*LSTR + kq] = h4;
            *(ushort4*)&As_lo[arow*LSTR + kq] = l4;
            cvt1(pb.x,h4.x,l4.x); cvt1(pb.y,h4.y,l4.y); cvt1(pb.z,h4.z,l4.z); cvt1(pb.w,h4.w,l4.w);
            *(ushort4*)&Bs_hi[arow*LSTR + kq] = h4;
            *(ushort4*)&Bs_lo[arow*LSTR + kq] = l4;
        }
        __syncthreads();
        if (k0 + 32 < 512) {
            pa = *(const float4*)(aptr + k0 + 32);
            pb = *(const float4*)(bptr + k0 + 32);
        }
        bf16x8 ah, al, bh, bl;
        {
            int r = (qr + fr) * LSTR + kg;
            ah = *(const bf16x8*)&As_hi[r]; al = *(const bf16x8*)&As_lo[r];
        }
        {
            int r = (qc + fr) * LSTR + kg;
            bh = *(const bf16x8*)&Bs_hi[r]; bl = *(const bf16x8*)&Bs_lo[r];
        }
        acc = __builtin_amdgcn_mfma_f32_16x16x32_bf16(ah, bh, acc, 0, 0, 0);
        acc = __builtin_amdgcn_mfma_f32_16x16x32_bf16(ah, bl, acc, 0, 0, 0);
        acc = __builtin_amdgcn_mfma_f32_16x16x32_bf16(al, bh, acc, 0, 0, 0);
        __syncthreads();
    }
    // reduce sumsq across the 8 threads sharing a row (consecutive lanes)
    ssA += __shfl_xor(ssA, 1); ssA += __shfl_xor(ssA, 2); ssA += __shfl_xor(ssA, 4);
    ssB += __shfl_xor(ssB, 1); ssB += __shfl_xor(ssB, 2); ssB += __shfl_xor(ssB, 4);
    if ((tid & 7) == 0) { snA[arow] = ssA; snB[arow] = ssB; }
    __syncthreads();
    const float fw0 = finw[0], fw1 = finw[1], fb = finb[0];
    const int rbase = (lane >> 4) * 4, lc = qc + (lane & 15);
    #pragma unroll
    for (int r = 0; r < 4; ++r) {
        int lr = qr + rbase + r;
        float na = fmaxf(sqrtf(snA[lr]), 1e-6f);
        float nb = fmaxf(sqrtf(snB[lc]), 1e-6f);
        int t = t0 + lr, d = d0 + lc;
        float cosv = acc[r] / (na * nb);
        float fin = sigmoidf_(cosv * fw0 + iou[t * 256 + d] * fw1 + fb);
        Mh[t * 256 + d] = __float2half(expf(fin * LAMF));
    }
}

// ============ Sinkhorn: M in registers (half2), r/c in LDS, 2 barriers/iter =
__global__ __launch_bounds__(1024) void sinkhorn2(const __half* __restrict__ Mh,
    float* __restrict__ gr, float* __restrict__ gc)
{
    __shared__ float r[256], c[256], red[8];
    const int tid = threadIdx.x;
    const int q = tid >> 2, sub = tid & 3;
    uint rm[32], cm[32];
    const uint* rp = (const uint*)(Mh + q * 256 + sub * 64);
    #pragma unroll
    for (int u = 0; u < 32; ++u) rm[u] = rp[u];
    #pragma unroll
    for (int u = 0; u < 32; ++u) {
        ushort h0 = *(const ushort*)(Mh + (sub * 64 + 2*u) * 256 + q);
        ushort h1 = *(const ushort*)(Mh + (sub * 64 + 2*u + 1) * 256 + q);
        cm[u] = (uint)h0 | ((uint)h1 << 16);
    }
    if (tid < 256) c[tid] = 1.0f;
    if (tid == 0) red[1] = 1.0f / SVF;    // Sr_prev s.t. c256 == 1
    __syncthreads();

    #pragma unroll 1
    for (int it = 0; it < 8; ++it) {
        // ---- window 1: row dots (uses c) + Sc reduce
        float c256 = 1.0f / (SVF * red[1]);
        float acc = 0.f;
        #pragma unroll
        for (int u = 0; u < 32; ++u) {
            __half2 h2 = __builtin_bit_cast(__half2, rm[u]);
            float2 cc = *(const float2*)&c[sub * 64 + 2*u];
            acc = fmaf(__low2float(h2), cc.x, acc);
            acc = fmaf(__high2float(h2), cc.y, acc);
        }
        acc += __shfl_xor(acc, 1); acc += __shfl_xor(acc, 2);
        if (tid < 64) {
            float s = c[tid] + c[tid+64] + c[tid+128] + c[tid+192];
            #pragma unroll
            for (int o = 32; o; o >>= 1) s += __shfl_down(s, o);
            if (tid == 0) red[0] = s + c256;      // Sc (incl border col)
        }
        if (sub == 0) r[q] = 1.0f / (acc + SVF * c256);
        __syncthreads();
        // ---- window 2: col dots (uses r) + Sr reduce
        float r256 = 1.0f / (SVF * red[0]);
        float acc2 = 0.f;
        #pragma unroll
        for (int u = 0; u < 32; ++u) {
            __half2 h2 = __builtin_bit_cast(__half2, cm[u]);
            float2 rr2 = *(const float2*)&r[sub * 64 + 2*u];
            acc2 = fmaf(__low2float(h2), rr2.x, acc2);
            acc2 = fmaf(__high2float(h2), rr2.y, acc2);
        }
        acc2 += __shfl_xor(acc2, 1); acc2 += __shfl_xor(acc2, 2);
        if (tid < 64) {
            float s = r[tid] + r[tid+64] + r[tid+128] + r[tid+192];
            #pragma unroll
            for (int o = 32; o; o >>= 1) s += __shfl_down(s, o);
            if (tid == 0) red[1] = s + r256;      // Sr (incl border row)
        }
        if (sub == 0) c[q] = 1.0f / (acc2 + SVF * r256);
        __syncthreads();
    }
    if (tid < 256) { gr[tid] = r[tid]; gc[tid] = c[tid]; }
}

// ============ final output assembly =========================================
__global__ __launch_bounds__(256) void final_kernel(const __half* __restrict__ Mh,
    const float* __restrict__ r, const float* __restrict__ c,
    const float* __restrict__ gt, float* __restrict__ out)
{
    const int bid = blockIdx.x, tid = threadIdx.x;
    if (bid < 256) {
        int k = bid * 256 + tid;
        out[k] = __half2float(Mh[k]) * r[bid] * c[tid];
    } else if (bid < 512) {
        int k = (bid - 256) * 256 + tid;
        out[EH + k] = gt[k];
    } else if (tid == 0) {
        out[2 * EH]     = 256.0f;
        out[2 * EH + 1] = 256.0f;
    }
}

extern "C" void kernel_launch(void* const* d_in, const int* in_sizes, int n_in,
                              void* d_out, int out_size, void* d_ws, size_t ws_size,
                              hipStream_t stream)
{
    const float* x       = (const float*)d_in[0];
    const float* coords  = (const float*)d_in[1];
    const float* co      = (const float*)d_in[2];
    const float* gt      = (const float*)d_in[3];
    const float* W_enc   = (const float*)d_in[5];
    const float* b_enc   = (const float*)d_in[6];
    const float* app_W1  = (const float*)d_in[7];
    const float* app_b1  = (const float*)d_in[8];
    const float* app_w2  = (const float*)d_in[9];
    const float* app_b2  = (const float*)d_in[10];
    const float* geo_W1  = (const float*)d_in[11];
    const float* geo_b1  = (const float*)d_in[12];
    const float* geo_w2  = (const float*)d_in[13];
    const float* geo_b2  = (const float*)d_in[14];
    const float* aff_w   = (const float*)d_in[15];
    const float* aff_b   = (const float*)d_in[16];
    const float* W_self  = (const float*)d_in[17];
    const float* W_nbr   = (const float*)d_in[18];
    const float* b_mp    = (const float*)d_in[19];
    const float* fin_w   = (const float*)d_in[20];
    const float* fin_b   = (const float*)d_in[21];
    float* out = (float*)d_out;

    // ---- workspace layout (stream-order-safe aliasing, peak 5,898,240 B)
    char* W = (char*)d_ws;
    float*  P     = (float*)(W + 0);         // [4][512][512] (dead after reduce)
    float*  h     = (float*)(W + 4849664);   // [512][512]
    float*  C45   = (float*)(W + 0);         // [512][1024] (Hn | Hs)  aliases P
    float*  C23   = (float*)(W + 2097152);   // [512][256]  (Aapp | Bapp)
    float*  ewT0  = (float*)(W + 2621440);   // [256 d][256 t]
    float*  ew2   = (float*)(W + 2883584);   // [256 t][256 d]
    float*  iou1  = (float*)(W + 3145728);   // [256][256]
    __half* Mh    = (__half*)(W + 3407872);  // [256][256] fp16
    float*  grv   = (float*)(W + 3538944);
    float*  gcv   = (float*)(W + 3543040);
    float*  outm  = (float*)(W + 3670016);   // [512][512]

    // 1) encoder partials: P[z] = x @ W_enc[z-slice]
    gemm64<0><<<dim3(8, 8, 4), 256, 0, stream>>>(x, nullptr, W_enc, nullptr, nullptr,
        nullptr, nullptr, P, nullptr);
    // 2) h = relu(sum_z P + b_enc)
    enc_reduce<<<256, 256, 0, stream>>>(P, b_enc, h);
    // 3) C45 = h@[Wnbr|Wself], C23 = h@[W1a|W1b]   (one fused launch)
    gemm64<1><<<dim3(20, 8), 256, 0, stream>>>(h, nullptr, W_nbr, W_self, app_W1,
        nullptr, nullptr, C45, C23);
    // 4) per-edge ew + iou (geo MLP inlined)
    edge_geo_kernel<<<dim3(16, 16, 2), 256, 0, stream>>>(C23, coords, geo_W1, geo_b1,
        app_b1, app_w2, app_b2, geo_w2, geo_b2, aff_w, aff_b, co, ewT0, ew2, iou1);
    // 5) outm = relu(ew@Hn + Hs + b_mp)
    gemm64<2><<<dim3(8, 8), 256, 0, stream>>>(ew2, ewT0, C45, nullptr, nullptr,
        C45, b_mp, outm, nullptr);
    // 6) gram + norms + fin + M0(fp16)
    gram32<<<dim3(8, 8), 256, 0, stream>>>(outm, iou1, fin_w, fin_b, Mh);
    // 7) Sinkhorn scale vectors
    sinkhorn2<<<1, 1024, 0, stream>>>(Mh, grv, gcv);
    // 8) final output assembly
    final_kernel<<<513, 256, 0, stream>>>(Mh, grv, gcv, gt, out);
}